// Round 12
// baseline (102.373 us; speedup 1.0000x reference)
//
#include <hip/hip_runtime.h>
#include <hip/hip_bf16.h>

#define N_NODES 50000
#define HID     256
#define N_EDGES 300000
#define NT      32   // nodes per GEMM tile
#define NTILES  ((N_NODES + NT - 1) / NT)
#define NBINS   64           // src>>10 -> bins 0..48
#define SBLK    128          // sort blocks
#define CHUNK   ((N_EDGES + SBLK - 1) / SBLK)   // 2344
#define EBLK    1024         // sorted-edge blocks
#define EPB     ((N_EDGES + EBLK - 1) / EBLK)   // 293 edges per block

typedef __attribute__((ext_vector_type(8))) short bf16x8;
typedef __attribute__((ext_vector_type(4))) float f32x4;

__device__ __forceinline__ unsigned short f2bf(float f) {
  unsigned int u = __float_as_uint(f);
  u = (u + 0x7FFFu + ((u >> 16) & 1u)) >> 16;   // RNE
  return (unsigned short)u;
}
__device__ __forceinline__ float bflo(unsigned int u) { return __uint_as_float(u << 16); }
__device__ __forceinline__ float bfhi(unsigned int u) { return __uint_as_float(u & 0xFFFF0000u); }

__device__ __forceinline__ bf16x8 cvt8(float4 u, float4 v) {
  bf16x8 r;
  r[0] = (short)f2bf(u.x); r[1] = (short)f2bf(u.y);
  r[2] = (short)f2bf(u.z); r[3] = (short)f2bf(u.w);
  r[4] = (short)f2bf(v.x); r[5] = (short)f2bf(v.y);
  r[6] = (short)f2bf(v.z); r[7] = (short)f2bf(v.w);
  return r;
}

struct StageRegs { float4 a, b, c, d; };

__device__ __forceinline__ void load_tile(const float* __restrict__ E, int tile,
                                          int srow, int sg, StageRegs& s) {
  int grow = tile * NT + srow;
  if (grow < N_NODES) {
    const float4* p = reinterpret_cast<const float4*>(E + (size_t)grow * HID + sg * 8);
    s.a = p[0]; s.b = p[1]; s.c = p[32]; s.d = p[33];
  } else {
    s.a = s.b = s.c = s.d = make_float4(0.f, 0.f, 0.f, 0.f);
  }
}

// ---- kernel 1: Wcat^T in MFMA-fragment order (coalesced reads).
__global__ __launch_bounds__(128) void pack_w_kernel(
    const float* __restrict__ W1, unsigned short* __restrict__ Wtf) {
  int k = blockIdx.x;          // 0..255
  int t = threadIdx.x;         // 0..127
  int half = t >> 6;
  int jj = (t & 63) * 4;
  const float4 v = *reinterpret_cast<const float4*>(
      W1 + (size_t)(half ? (HID + k) : k) * HID + jj);
  float vv[4] = {v.x, v.y, v.z, v.w};
#pragma unroll
  for (int e = 0; e < 4; ++e) {
    int j = half * HID + jj + e;
    int f    = (j >> 4) * 8 + (k >> 5);
    int lane = (j & 15) | (((k >> 3) & 3) << 4);
    int elem = k & 7;
    Wtf[f * 512 + lane * 8 + elem] = f2bf(vv[e]);
  }
}

// ---- counting sort by src bucket (atomic-contention-free) ----
__global__ __launch_bounds__(256) void hist_kernel(const int* __restrict__ idx,
                                                   int* __restrict__ blockhist) {
  __shared__ int h[NBINS];
  for (int i = threadIdx.x; i < NBINS; i += 256) h[i] = 0;
  __syncthreads();
  int b = blockIdx.x;
  int lo = b * CHUNK, hi = min(lo + CHUNK, N_EDGES);
  for (int e = lo + threadIdx.x; e < hi; e += 256)
    atomicAdd(&h[idx[e] >> 10], 1);
  __syncthreads();
  for (int i = threadIdx.x; i < NBINS; i += 256)
    blockhist[b * NBINS + i] = h[i];
}

__global__ __launch_bounds__(64) void scan_kernel(const int* __restrict__ blockhist,
                                                  int* __restrict__ base2) {
  int bin = threadIdx.x;   // one wave, lane = bin
  int tot = 0;
  for (int b = 0; b < SBLK; ++b) tot += blockhist[b * NBINS + bin];
  int incl = tot;
#pragma unroll
  for (int off = 1; off < 64; off <<= 1) {
    int v = __shfl_up(incl, off, 64);
    if (bin >= off) incl += v;
  }
  int run = incl - tot;    // exclusive bin base
  for (int b = 0; b < SBLK; ++b) {
    base2[b * NBINS + bin] = run;
    run += blockhist[b * NBINS + bin];
  }
}

__global__ __launch_bounds__(256) void scatter_kernel(const int* __restrict__ idx,
                                                      const int* __restrict__ base2,
                                                      int4* __restrict__ eperm) {
  __shared__ int cur[NBINS];
  int b = blockIdx.x;
  for (int i = threadIdx.x; i < NBINS; i += 256) cur[i] = base2[b * NBINS + i];
  __syncthreads();
  int lo = b * CHUNK, hi = min(lo + CHUNK, N_EDGES);
  for (int e = lo + threadIdx.x; e < hi; e += 256) {
    int s = idx[e], t = idx[N_EDGES + e];
    int pos = atomicAdd(&cur[s >> 10], 1);   // LDS atomic, block-local
    eperm[pos] = make_int4(s, t, e, 0);
  }
}

// ---- kernel 2: weights-stationary streaming GEMM (round-11 exact).
__global__ __launch_bounds__(512, 2) void gemm_kernel(
    const float* __restrict__ E, const unsigned short* __restrict__ Wtf,
    const float* __restrict__ b1, unsigned short* __restrict__ P) {
  __shared__ alignas(16) char lds0[16384];
  __shared__ alignas(16) char lds1[16384];
  const int tid  = threadIdx.x;
  const int lane = tid & 63;
  const int w    = tid >> 6;

  bf16x8 a[4][8];
#pragma unroll
  for (int m = 0; m < 4; ++m)
#pragma unroll
    for (int kk = 0; kk < 8; ++kk)
      a[m][kk] = *reinterpret_cast<const bf16x8*>(
          Wtf + (((size_t)(w * 4 + m) * 8 + kk) << 9) + lane * 8);

  float4 bv[4];
#pragma unroll
  for (int m = 0; m < 4; ++m) {
    int fm = w * 4 + m;
    bv[m] = (fm < 16) ? *reinterpret_cast<const float4*>(b1 + fm * 16 + ((lane >> 4) << 2))
                      : make_float4(0.f, 0.f, 0.f, 0.f);
  }

  const int srow = tid >> 4;
  const int sg   = tid & 15;
  const int woff0 = srow * 512 + ((sg * 16) ^ ((srow & 7) << 4));
  const int woff1 = srow * 512 + (((sg + 16) * 16) ^ ((srow & 7) << 4));
  const int G = gridDim.x;

  auto write_tile = [&](char* buf, const StageRegs& s) {
    *reinterpret_cast<bf16x8*>(&buf[woff0]) = cvt8(s.a, s.b);
    *reinterpret_cast<bf16x8*>(&buf[woff1]) = cvt8(s.c, s.d);
  };

  auto compute_store = [&](const char* buf, int tt) {
    f32x4 acc[4][2] = {};
#pragma unroll
    for (int n = 0; n < 2; ++n) {
      int r   = n * 16 + (lane & 15);
      int rb  = r * 512;
      int sw  = (r & 7) << 4;
      int kb0 = (lane >> 4) << 4;
      bf16x8 bfr[8];
#pragma unroll
      for (int kk = 0; kk < 8; ++kk)
        bfr[kk] = *reinterpret_cast<const bf16x8*>(&buf[rb + ((kk * 64 + kb0) ^ sw)]);
#pragma unroll
      for (int kk = 0; kk < 8; ++kk)
#pragma unroll
        for (int m = 0; m < 4; ++m)
          acc[m][n] = __builtin_amdgcn_mfma_f32_16x16x32_bf16(a[m][kk], bfr[kk], acc[m][n], 0, 0, 0);
    }
#pragma unroll
    for (int m = 0; m < 4; ++m) {
      int pcb = (w * 4 + m) * 16 + ((lane >> 4) << 2);
#pragma unroll
      for (int n = 0; n < 2; ++n) {
        int node = tt * NT + n * 16 + (lane & 15);
        if (node < N_NODES) {
          ushort4 o;
          o.x = f2bf(acc[m][n][0] + bv[m].x);
          o.y = f2bf(acc[m][n][1] + bv[m].y);
          o.z = f2bf(acc[m][n][2] + bv[m].z);
          o.w = f2bf(acc[m][n][3] + bv[m].w);
          *reinterpret_cast<ushort4*>(P + (size_t)node * 512 + pcb) = o;
        }
      }
    }
  };

  int t = blockIdx.x;
  if (t >= NTILES) return;
  StageRegs sX, sY;
  load_tile(E, t, srow, sg, sX);
  if (t + G < NTILES) load_tile(E, t + G, srow, sg, sY);
  write_tile(lds0, sX);
  if (t + 2 * G < NTILES) load_tile(E, t + 2 * G, srow, sg, sX);
  __syncthreads();

  while (true) {
    if (t + G < NTILES) {
      write_tile(lds1, sY);
      if (t + 3 * G < NTILES) load_tile(E, t + 3 * G, srow, sg, sY);
    }
    compute_store(lds0, t);
    if (t + G >= NTILES) break;
    __syncthreads();
    t += G;
    if (t + G < NTILES) {
      write_tile(lds0, sX);
      if (t + 3 * G < NTILES) load_tile(E, t + 3 * G, srow, sg, sX);
    }
    compute_store(lds1, t);
    if (t + G >= NTILES) break;
    __syncthreads();
    t += G;
  }
}

// ---- kernel 3a: sorted edge gather. Each XCD owns a contiguous eperm slice
// (swz = (b&7)*128 + b>>3) -> ~1.6MB src working set per XCD L2, ~6x reuse.
__global__ __launch_bounds__(256) void edge_sorted_kernel(
    const int4* __restrict__ eperm, const unsigned short* __restrict__ P,
    const float* __restrict__ W2, const float* __restrict__ b2,
    float* __restrict__ out) {
  const int tid  = threadIdx.x;
  const int lane = tid & 63;
  const int l32  = lane & 31;
  const int half = lane >> 5;
  const int swz  = ((blockIdx.x & 7) << 7) + (blockIdx.x >> 3);
  const int start = swz * EPB;
  const int end   = min(start + EPB, N_EDGES);
  const int hid   = (tid >> 6) * 2 + half;   // 0..7 half-wave id in block
  const float4 w0 = *reinterpret_cast<const float4*>(W2 + l32 * 8);
  const float4 w1 = *reinterpret_cast<const float4*>(W2 + l32 * 8 + 4);
  const float bias = b2[0];
  for (int i = start + hid; i < end; i += 8) {
    int4 q = eperm[i];
    uint4 ua = *reinterpret_cast<const uint4*>(P + (size_t)q.x * 512 + l32 * 8);
    uint4 ub = *reinterpret_cast<const uint4*>(P + (size_t)q.y * 512 + 256 + l32 * 8);
    float h0 = fmaxf(bflo(ua.x) + bflo(ub.x), 0.f);
    float h1 = fmaxf(bfhi(ua.x) + bfhi(ub.x), 0.f);
    float h2 = fmaxf(bflo(ua.y) + bflo(ub.y), 0.f);
    float h3 = fmaxf(bfhi(ua.y) + bfhi(ub.y), 0.f);
    float h4 = fmaxf(bflo(ua.z) + bflo(ub.z), 0.f);
    float h5 = fmaxf(bfhi(ua.z) + bfhi(ub.z), 0.f);
    float h6 = fmaxf(bflo(ua.w) + bflo(ub.w), 0.f);
    float h7 = fmaxf(bfhi(ua.w) + bfhi(ub.w), 0.f);
    float acc = h0 * w0.x + h1 * w0.y + h2 * w0.z + h3 * w0.w
              + h4 * w1.x + h5 * w1.y + h6 * w1.z + h7 * w1.w;
#pragma unroll
    for (int off = 1; off < 32; off <<= 1)
      acc += __shfl_xor(acc, off, 64);
    if (l32 == 0) out[q.z] = acc + bias;
  }
}

// ---- kernel 3b: fallback unsorted (round-4 proven), used if ws too small.
__global__ __launch_bounds__(256) void edge_kernel(
    const int* __restrict__ idx, const unsigned short* __restrict__ P,
    const float* __restrict__ W2, const float* __restrict__ b2,
    float* __restrict__ out) {
  const int tid  = threadIdx.x;
  const int lane = tid & 63;
  const int l32  = lane & 31;
  const int half = lane >> 5;
  const int wv     = blockIdx.x * 4 + (tid >> 6);
  const int nwaves = gridDim.x * 4;
  const float4 w0 = *reinterpret_cast<const float4*>(W2 + l32 * 8);
  const float4 w1 = *reinterpret_cast<const float4*>(W2 + l32 * 8 + 4);
  const float bias = b2[0];
  for (int ep = wv; ep < N_EDGES / 2; ep += nwaves) {
    int e = ep * 2 + half;
    int s = idx[e];
    int t = idx[N_EDGES + e];
    uint4 ua = *reinterpret_cast<const uint4*>(P + (size_t)s * 512 + l32 * 8);
    uint4 ub = *reinterpret_cast<const uint4*>(P + (size_t)t * 512 + 256 + l32 * 8);
    float h0 = fmaxf(bflo(ua.x) + bflo(ub.x), 0.f);
    float h1 = fmaxf(bfhi(ua.x) + bfhi(ub.x), 0.f);
    float h2 = fmaxf(bflo(ua.y) + bflo(ub.y), 0.f);
    float h3 = fmaxf(bfhi(ua.y) + bfhi(ub.y), 0.f);
    float h4 = fmaxf(bflo(ua.z) + bflo(ub.z), 0.f);
    float h5 = fmaxf(bfhi(ua.z) + bfhi(ub.z), 0.f);
    float h6 = fmaxf(bflo(ua.w) + bflo(ub.w), 0.f);
    float h7 = fmaxf(bfhi(ua.w) + bfhi(ub.w), 0.f);
    float acc = h0 * w0.x + h1 * w0.y + h2 * w0.z + h3 * w0.w
              + h4 * w1.x + h5 * w1.y + h6 * w1.z + h7 * w1.w;
#pragma unroll
    for (int off = 1; off < 32; off <<= 1)
      acc += __shfl_xor(acc, off, 64);
    if (l32 == 0) out[e] = acc + bias;
  }
}

extern "C" void kernel_launch(void* const* d_in, const int* in_sizes, int n_in,
                              void* d_out, int out_size, void* d_ws, size_t ws_size,
                              hipStream_t stream) {
  const float* E   = (const float*)d_in[0];
  const int*   idx = (const int*)d_in[1];
  const float* W1  = (const float*)d_in[2];
  const float* b1  = (const float*)d_in[3];
  const float* W2  = (const float*)d_in[4];
  const float* b2  = (const float*)d_in[5];
  float* out = (float*)d_out;

  char* ws = (char*)d_ws;
  unsigned short* Wtf = (unsigned short*)ws;                 // 256 KiB
  unsigned short* P   = (unsigned short*)(ws + 262144);      // 51.2 MB
  size_t off = 262144 + 51200000;
  int*  blockhist = (int*)(ws + off);                        // 32 KB
  int*  base2     = (int*)(ws + off + 32768);                // 32 KB
  int4* eperm     = (int4*)(ws + off + 65536);               // 4.8 MB
  size_t need = off + 65536 + (size_t)(EBLK * EPB) * 16;

  hipLaunchKernelGGL(pack_w_kernel, dim3(HID), dim3(128), 0, stream, W1, Wtf);
  if (ws_size >= need) {
    hipLaunchKernelGGL(hist_kernel, dim3(SBLK), dim3(256), 0, stream, idx, blockhist);
    hipLaunchKernelGGL(scan_kernel, dim3(1), dim3(64), 0, stream, blockhist, base2);
    hipLaunchKernelGGL(scatter_kernel, dim3(SBLK), dim3(256), 0, stream, idx, base2, eperm);
    hipLaunchKernelGGL(gemm_kernel, dim3(256), dim3(512), 0, stream, E, Wtf, b1, P);
    hipLaunchKernelGGL(edge_sorted_kernel, dim3(EBLK), dim3(256), 0, stream,
                       eperm, P, W2, b2, out);
  } else {
    hipLaunchKernelGGL(gemm_kernel, dim3(256), dim3(512), 0, stream, E, Wtf, b1, P);
    hipLaunchKernelGGL(edge_kernel, dim3(2048), dim3(256), 0, stream, idx, P, W2, b2, out);
  }
}

// Round 13
// 80.924 us; speedup vs baseline: 1.2651x; 1.2651x over previous
//
#include <hip/hip_runtime.h>
#include <hip/hip_bf16.h>

#define N_NODES 50000
#define HID     256
#define N_EDGES 300000
#define NT      32   // nodes per GEMM tile
#define NTILES  ((N_NODES + NT - 1) / NT)

typedef __attribute__((ext_vector_type(8))) short bf16x8;
typedef __attribute__((ext_vector_type(4))) float f32x4;

__device__ __forceinline__ unsigned short f2bf(float f) {
  unsigned int u = __float_as_uint(f);
  u = (u + 0x7FFFu + ((u >> 16) & 1u)) >> 16;   // RNE
  return (unsigned short)u;
}
__device__ __forceinline__ float bflo(unsigned int u) { return __uint_as_float(u << 16); }
__device__ __forceinline__ float bfhi(unsigned int u) { return __uint_as_float(u & 0xFFFF0000u); }

__device__ __forceinline__ bf16x8 cvt8(float4 u, float4 v) {
  bf16x8 r;
  r[0] = (short)f2bf(u.x); r[1] = (short)f2bf(u.y);
  r[2] = (short)f2bf(u.z); r[3] = (short)f2bf(u.w);
  r[4] = (short)f2bf(v.x); r[5] = (short)f2bf(v.y);
  r[6] = (short)f2bf(v.z); r[7] = (short)f2bf(v.w);
  return r;
}

struct StageRegs { float4 a, b, c, d; };

__device__ __forceinline__ void load_tile(const float* __restrict__ E, int tile,
                                          int srow, int sg, StageRegs& s) {
  int grow = tile * NT + srow;
  if (grow < N_NODES) {
    const float4* p = reinterpret_cast<const float4*>(E + (size_t)grow * HID + sg * 8);
    s.a = p[0]; s.b = p[1]; s.c = p[32]; s.d = p[33];
  } else {
    s.a = s.b = s.c = s.d = make_float4(0.f, 0.f, 0.f, 0.f);
  }
}

// ---- kernel 1: Wcat^T in MFMA-fragment order (coalesced reads).
__global__ __launch_bounds__(128) void pack_w_kernel(
    const float* __restrict__ W1, unsigned short* __restrict__ Wtf) {
  int k = blockIdx.x;          // 0..255
  int t = threadIdx.x;         // 0..127
  int half = t >> 6;
  int jj = (t & 63) * 4;
  const float4 v = *reinterpret_cast<const float4*>(
      W1 + (size_t)(half ? (HID + k) : k) * HID + jj);
  float vv[4] = {v.x, v.y, v.z, v.w};
#pragma unroll
  for (int e = 0; e < 4; ++e) {
    int j = half * HID + jj + e;
    int f    = (j >> 4) * 8 + (k >> 5);
    int lane = (j & 15) | (((k >> 3) & 3) << 4);
    int elem = k & 7;
    Wtf[f * 512 + lane * 8 + elem] = f2bf(vv[e]);
  }
}

// ---- kernel 2: weights-stationary streaming GEMM, depth-2 prefetch,
// deferred epilogue: tile t's global stores issue at the TOP of phase t+1 so
// they drain under the next phase's compute instead of stalling at the
// barrier's vmcnt(0) (same mechanism as the r11 load fix, store side).
__global__ __launch_bounds__(512, 2) void gemm_kernel(
    const float* __restrict__ E, const unsigned short* __restrict__ Wtf,
    const float* __restrict__ b1, unsigned short* __restrict__ P) {
  __shared__ alignas(16) char lds0[16384];   // 32 rows x 512B bf16, XOR-swizzled
  __shared__ alignas(16) char lds1[16384];
  const int tid  = threadIdx.x;
  const int lane = tid & 63;
  const int w    = tid >> 6;                 // 0..7

  // persistent A fragments: wave w owns P-cols [w*64, w*64+64) x K=256 (128 VGPR)
  bf16x8 a[4][8];
#pragma unroll
  for (int m = 0; m < 4; ++m)
#pragma unroll
    for (int kk = 0; kk < 8; ++kk)
      a[m][kk] = *reinterpret_cast<const bf16x8*>(
          Wtf + (((size_t)(w * 4 + m) * 8 + kk) << 9) + lane * 8);

  float4 bv[4];
#pragma unroll
  for (int m = 0; m < 4; ++m) {
    int fm = w * 4 + m;
    bv[m] = (fm < 16) ? *reinterpret_cast<const float4*>(b1 + fm * 16 + ((lane >> 4) << 2))
                      : make_float4(0.f, 0.f, 0.f, 0.f);
  }

  const int srow = tid >> 4;               // 0..31
  const int sg   = tid & 15;
  const int woff0 = srow * 512 + ((sg * 16) ^ ((srow & 7) << 4));
  const int woff1 = srow * 512 + (((sg + 16) * 16) ^ ((srow & 7) << 4));
  const int G = gridDim.x;

  auto write_tile = [&](char* buf, const StageRegs& s) {
    *reinterpret_cast<bf16x8*>(&buf[woff0]) = cvt8(s.a, s.b);
    *reinterpret_cast<bf16x8*>(&buf[woff1]) = cvt8(s.c, s.d);
  };

  f32x4 acc[4][2];

  auto compute = [&](const char* buf) {
#pragma unroll
    for (int n = 0; n < 2; ++n) {
      int r   = n * 16 + (lane & 15);
      int rb  = r * 512;
      int sw  = (r & 7) << 4;
      int kb0 = (lane >> 4) << 4;
      bf16x8 bfr[8];
#pragma unroll
      for (int kk = 0; kk < 8; ++kk)
        bfr[kk] = *reinterpret_cast<const bf16x8*>(&buf[rb + ((kk * 64 + kb0) ^ sw)]);
#pragma unroll
      for (int m = 0; m < 4; ++m)
        acc[m][n] = f32x4{0.f, 0.f, 0.f, 0.f};
#pragma unroll
      for (int kk = 0; kk < 8; ++kk)
#pragma unroll
        for (int m = 0; m < 4; ++m)
          acc[m][n] = __builtin_amdgcn_mfma_f32_16x16x32_bf16(a[m][kk], bfr[kk], acc[m][n], 0, 0, 0);
    }
  };

  auto store_acc = [&](int tt) {
#pragma unroll
    for (int m = 0; m < 4; ++m) {
      int pcb = (w * 4 + m) * 16 + ((lane >> 4) << 2);
#pragma unroll
      for (int n = 0; n < 2; ++n) {
        int node = tt * NT + n * 16 + (lane & 15);
        if (node < N_NODES) {
          ushort4 o;
          o.x = f2bf(acc[m][n][0] + bv[m].x);
          o.y = f2bf(acc[m][n][1] + bv[m].y);
          o.z = f2bf(acc[m][n][2] + bv[m].z);
          o.w = f2bf(acc[m][n][3] + bv[m].w);
          *reinterpret_cast<ushort4*>(P + (size_t)node * 512 + pcb) = o;
        }
      }
    }
  };

  int t = blockIdx.x;
  if (t >= NTILES) return;
  StageRegs sX, sY;
  // prologue: lds0 <- tile t; sY <- t+G; sX <- t+2G (depth-2 in flight)
  load_tile(E, t, srow, sg, sX);
  if (t + G < NTILES) load_tile(E, t + G, srow, sg, sY);
  write_tile(lds0, sX);
  if (t + 2 * G < NTILES) load_tile(E, t + 2 * G, srow, sg, sX);
  __syncthreads();

  int tprev = -1;
  while (true) {
    // phase A: store prev tile's acc, pre-write lds1 + prefetch, compute lds0
    if (tprev >= 0) store_acc(tprev);
    if (t + G < NTILES) {
      write_tile(lds1, sY);
      if (t + 3 * G < NTILES) load_tile(E, t + 3 * G, srow, sg, sY);
    }
    compute(lds0);
    tprev = t;
    if (t + G >= NTILES) break;
    __syncthreads();
    t += G;
    // phase B: mirrored on lds1 / sX
    store_acc(tprev);
    if (t + G < NTILES) {
      write_tile(lds0, sX);
      if (t + 3 * G < NTILES) load_tile(E, t + 3 * G, srow, sg, sX);
    }
    compute(lds1);
    tprev = t;
    if (t + G >= NTILES) break;
    __syncthreads();
    t += G;
  }
  store_acc(tprev);   // final tile
}

// ---- kernel 3: 2 edges per wave (32 lanes each), 16B bf16x8 gathers (round-4 proven).
__global__ __launch_bounds__(256) void edge_kernel(
    const int* __restrict__ idx, const unsigned short* __restrict__ P,
    const float* __restrict__ W2, const float* __restrict__ b2,
    float* __restrict__ out) {
  const int tid  = threadIdx.x;
  const int lane = tid & 63;
  const int l32  = lane & 31;
  const int half = lane >> 5;
  const int wv     = blockIdx.x * 4 + (tid >> 6);
  const int nwaves = gridDim.x * 4;
  const float4 w0 = *reinterpret_cast<const float4*>(W2 + l32 * 8);
  const float4 w1 = *reinterpret_cast<const float4*>(W2 + l32 * 8 + 4);
  const float bias = b2[0];
  for (int ep = wv; ep < N_EDGES / 2; ep += nwaves) {
    int e = ep * 2 + half;
    int s = idx[e];
    int t = idx[N_EDGES + e];
    uint4 ua = *reinterpret_cast<const uint4*>(P + (size_t)s * 512 + l32 * 8);
    uint4 ub = *reinterpret_cast<const uint4*>(P + (size_t)t * 512 + 256 + l32 * 8);
    float h0 = fmaxf(bflo(ua.x) + bflo(ub.x), 0.f);
    float h1 = fmaxf(bfhi(ua.x) + bfhi(ub.x), 0.f);
    float h2 = fmaxf(bflo(ua.y) + bflo(ub.y), 0.f);
    float h3 = fmaxf(bfhi(ua.y) + bfhi(ub.y), 0.f);
    float h4 = fmaxf(bflo(ua.z) + bflo(ub.z), 0.f);
    float h5 = fmaxf(bfhi(ua.z) + bfhi(ub.z), 0.f);
    float h6 = fmaxf(bflo(ua.w) + bflo(ub.w), 0.f);
    float h7 = fmaxf(bfhi(ua.w) + bfhi(ub.w), 0.f);
    float acc = h0 * w0.x + h1 * w0.y + h2 * w0.z + h3 * w0.w
              + h4 * w1.x + h5 * w1.y + h6 * w1.z + h7 * w1.w;
#pragma unroll
    for (int off = 1; off < 32; off <<= 1)
      acc += __shfl_xor(acc, off, 64);   // stays within each 32-lane half
    if (l32 == 0) out[e] = acc + bias;
  }
}

extern "C" void kernel_launch(void* const* d_in, const int* in_sizes, int n_in,
                              void* d_out, int out_size, void* d_ws, size_t ws_size,
                              hipStream_t stream) {
  const float* E   = (const float*)d_in[0];
  const int*   idx = (const int*)d_in[1];
  const float* W1  = (const float*)d_in[2];
  const float* b1  = (const float*)d_in[3];
  const float* W2  = (const float*)d_in[4];
  const float* b2  = (const float*)d_in[5];
  float* out = (float*)d_out;

  unsigned short* Wtf = (unsigned short*)d_ws;                   // 256 KiB
  unsigned short* P   = (unsigned short*)((char*)d_ws + 262144); // 48.83 MiB

  hipLaunchKernelGGL(pack_w_kernel, dim3(HID), dim3(128), 0, stream, W1, Wtf);
  hipLaunchKernelGGL(gemm_kernel, dim3(256), dim3(512), 0, stream, E, Wtf, b1, P);
  hipLaunchKernelGGL(edge_kernel, dim3(2048), dim3(256), 0, stream, idx, P, W2, b2, out);
}

// Round 14
// 78.352 us; speedup vs baseline: 1.3066x; 1.0328x over previous
//
#include <hip/hip_runtime.h>
#include <hip/hip_bf16.h>

#define N_NODES 50000
#define HID     256
#define N_EDGES 300000
#define NT      32   // nodes per GEMM tile
#define NTILES  ((N_NODES + NT - 1) / NT)

typedef __attribute__((ext_vector_type(8))) short bf16x8;
typedef __attribute__((ext_vector_type(4))) float f32x4;

__device__ __forceinline__ unsigned short f2bf(float f) {
  unsigned int u = __float_as_uint(f);
  u = (u + 0x7FFFu + ((u >> 16) & 1u)) >> 16;   // RNE
  return (unsigned short)u;
}
__device__ __forceinline__ float bflo(unsigned int u) { return __uint_as_float(u << 16); }
__device__ __forceinline__ float bfhi(unsigned int u) { return __uint_as_float(u & 0xFFFF0000u); }

__device__ __forceinline__ bf16x8 cvt8(float4 u, float4 v) {
  bf16x8 r;
  r[0] = (short)f2bf(u.x); r[1] = (short)f2bf(u.y);
  r[2] = (short)f2bf(u.z); r[3] = (short)f2bf(u.w);
  r[4] = (short)f2bf(v.x); r[5] = (short)f2bf(v.y);
  r[6] = (short)f2bf(v.z); r[7] = (short)f2bf(v.w);
  return r;
}

struct StageRegs { float4 a, b, c, d; };

__device__ __forceinline__ void load_tile(const float* __restrict__ E, int tile,
                                          int srow, int sg, StageRegs& s) {
  int grow = tile * NT + srow;
  if (grow < N_NODES) {
    const float4* p = reinterpret_cast<const float4*>(E + (size_t)grow * HID + sg * 8);
    s.a = p[0]; s.b = p[1]; s.c = p[32]; s.d = p[33];
  } else {
    s.a = s.b = s.c = s.d = make_float4(0.f, 0.f, 0.f, 0.f);
  }
}

// ---- kernel 1: Wcat^T in MFMA-fragment order (coalesced reads).
__global__ __launch_bounds__(128) void pack_w_kernel(
    const float* __restrict__ W1, unsigned short* __restrict__ Wtf) {
  int k = blockIdx.x;          // 0..255
  int t = threadIdx.x;         // 0..127
  int half = t >> 6;
  int jj = (t & 63) * 4;
  const float4 v = *reinterpret_cast<const float4*>(
      W1 + (size_t)(half ? (HID + k) : k) * HID + jj);
  float vv[4] = {v.x, v.y, v.z, v.w};
#pragma unroll
  for (int e = 0; e < 4; ++e) {
    int j = half * HID + jj + e;
    int f    = (j >> 4) * 8 + (k >> 5);
    int lane = (j & 15) | (((k >> 3) & 3) << 4);
    int elem = k & 7;
    Wtf[f * 512 + lane * 8 + elem] = f2bf(vv[e]);
  }
}

// ---- kernel 2: weights-stationary streaming GEMM (round-11 exact, best measured).
// Phase order: issue LDS-write + next global prefetch at phase TOP, then compute
// (~600cy) covers the load latency before __syncthreads' implicit vmcnt(0) drain.
__global__ __launch_bounds__(512, 2) void gemm_kernel(
    const float* __restrict__ E, const unsigned short* __restrict__ Wtf,
    const float* __restrict__ b1, unsigned short* __restrict__ P) {
  __shared__ alignas(16) char lds0[16384];   // 32 rows x 512B bf16, XOR-swizzled
  __shared__ alignas(16) char lds1[16384];
  const int tid  = threadIdx.x;
  const int lane = tid & 63;
  const int w    = tid >> 6;                 // 0..7

  // persistent A fragments: wave w owns P-cols [w*64, w*64+64) x K=256 (128 VGPR)
  bf16x8 a[4][8];
#pragma unroll
  for (int m = 0; m < 4; ++m)
#pragma unroll
    for (int kk = 0; kk < 8; ++kk)
      a[m][kk] = *reinterpret_cast<const bf16x8*>(
          Wtf + (((size_t)(w * 4 + m) * 8 + kk) << 9) + lane * 8);

  float4 bv[4];
#pragma unroll
  for (int m = 0; m < 4; ++m) {
    int fm = w * 4 + m;
    bv[m] = (fm < 16) ? *reinterpret_cast<const float4*>(b1 + fm * 16 + ((lane >> 4) << 2))
                      : make_float4(0.f, 0.f, 0.f, 0.f);
  }

  const int srow = tid >> 4;               // 0..31
  const int sg   = tid & 15;
  const int woff0 = srow * 512 + ((sg * 16) ^ ((srow & 7) << 4));
  const int woff1 = srow * 512 + (((sg + 16) * 16) ^ ((srow & 7) << 4));
  const int G = gridDim.x;

  auto write_tile = [&](char* buf, const StageRegs& s) {
    *reinterpret_cast<bf16x8*>(&buf[woff0]) = cvt8(s.a, s.b);
    *reinterpret_cast<bf16x8*>(&buf[woff1]) = cvt8(s.c, s.d);
  };

  auto compute_store = [&](const char* buf, int tt) {
    f32x4 acc[4][2] = {};
#pragma unroll
    for (int n = 0; n < 2; ++n) {
      int r   = n * 16 + (lane & 15);
      int rb  = r * 512;
      int sw  = (r & 7) << 4;
      int kb0 = (lane >> 4) << 4;
      bf16x8 bfr[8];
#pragma unroll
      for (int kk = 0; kk < 8; ++kk)
        bfr[kk] = *reinterpret_cast<const bf16x8*>(&buf[rb + ((kk * 64 + kb0) ^ sw)]);
#pragma unroll
      for (int kk = 0; kk < 8; ++kk)
#pragma unroll
        for (int m = 0; m < 4; ++m)
          acc[m][n] = __builtin_amdgcn_mfma_f32_16x16x32_bf16(a[m][kk], bfr[kk], acc[m][n], 0, 0, 0);
    }
#pragma unroll
    for (int m = 0; m < 4; ++m) {
      int pcb = (w * 4 + m) * 16 + ((lane >> 4) << 2);
#pragma unroll
      for (int n = 0; n < 2; ++n) {
        int node = tt * NT + n * 16 + (lane & 15);
        if (node < N_NODES) {
          ushort4 o;
          o.x = f2bf(acc[m][n][0] + bv[m].x);
          o.y = f2bf(acc[m][n][1] + bv[m].y);
          o.z = f2bf(acc[m][n][2] + bv[m].z);
          o.w = f2bf(acc[m][n][3] + bv[m].w);
          *reinterpret_cast<ushort4*>(P + (size_t)node * 512 + pcb) = o;
        }
      }
    }
  };

  int t = blockIdx.x;
  if (t >= NTILES) return;
  StageRegs sX, sY;
  // prologue: lds0 <- tile t; sY <- t+G; sX <- t+2G (depth-2 in flight)
  load_tile(E, t, srow, sg, sX);
  if (t + G < NTILES) load_tile(E, t + G, srow, sg, sY);
  write_tile(lds0, sX);
  if (t + 2 * G < NTILES) load_tile(E, t + 2 * G, srow, sg, sX);
  __syncthreads();

  while (true) {
    // phase A: pre-write lds1 (tile t+G) + issue prefetch t+3G, THEN compute lds0
    if (t + G < NTILES) {
      write_tile(lds1, sY);
      if (t + 3 * G < NTILES) load_tile(E, t + 3 * G, srow, sg, sY);
    }
    compute_store(lds0, t);
    if (t + G >= NTILES) break;
    __syncthreads();
    t += G;
    // phase B: pre-write lds0 + prefetch into sX, THEN compute lds1
    if (t + G < NTILES) {
      write_tile(lds0, sX);
      if (t + 3 * G < NTILES) load_tile(E, t + 3 * G, srow, sg, sX);
    }
    compute_store(lds1, t);
    if (t + G >= NTILES) break;
    __syncthreads();
    t += G;
  }
}

// ---- kernel 3: 2 edges per wave (32 lanes each), 16B bf16x8 gathers (round-4 proven).
__global__ __launch_bounds__(256) void edge_kernel(
    const int* __restrict__ idx, const unsigned short* __restrict__ P,
    const float* __restrict__ W2, const float* __restrict__ b2,
    float* __restrict__ out) {
  const int tid  = threadIdx.x;
  const int lane = tid & 63;
  const int l32  = lane & 31;
  const int half = lane >> 5;
  const int wv     = blockIdx.x * 4 + (tid >> 6);
  const int nwaves = gridDim.x * 4;
  const float4 w0 = *reinterpret_cast<const float4*>(W2 + l32 * 8);
  const float4 w1 = *reinterpret_cast<const float4*>(W2 + l32 * 8 + 4);
  const float bias = b2[0];
  for (int ep = wv; ep < N_EDGES / 2; ep += nwaves) {
    int e = ep * 2 + half;
    int s = idx[e];
    int t = idx[N_EDGES + e];
    uint4 ua = *reinterpret_cast<const uint4*>(P + (size_t)s * 512 + l32 * 8);
    uint4 ub = *reinterpret_cast<const uint4*>(P + (size_t)t * 512 + 256 + l32 * 8);
    float h0 = fmaxf(bflo(ua.x) + bflo(ub.x), 0.f);
    float h1 = fmaxf(bfhi(ua.x) + bfhi(ub.x), 0.f);
    float h2 = fmaxf(bflo(ua.y) + bflo(ub.y), 0.f);
    float h3 = fmaxf(bfhi(ua.y) + bfhi(ub.y), 0.f);
    float h4 = fmaxf(bflo(ua.z) + bflo(ub.z), 0.f);
    float h5 = fmaxf(bfhi(ua.z) + bfhi(ub.z), 0.f);
    float h6 = fmaxf(bflo(ua.w) + bflo(ub.w), 0.f);
    float h7 = fmaxf(bfhi(ua.w) + bfhi(ub.w), 0.f);
    float acc = h0 * w0.x + h1 * w0.y + h2 * w0.z + h3 * w0.w
              + h4 * w1.x + h5 * w1.y + h6 * w1.z + h7 * w1.w;
#pragma unroll
    for (int off = 1; off < 32; off <<= 1)
      acc += __shfl_xor(acc, off, 64);   // stays within each 32-lane half
    if (l32 == 0) out[e] = acc + bias;
  }
}

extern "C" void kernel_launch(void* const* d_in, const int* in_sizes, int n_in,
                              void* d_out, int out_size, void* d_ws, size_t ws_size,
                              hipStream_t stream) {
  const float* E   = (const float*)d_in[0];
  const int*   idx = (const int*)d_in[1];
  const float* W1  = (const float*)d_in[2];
  const float* b1  = (const float*)d_in[3];
  const float* W2  = (const float*)d_in[4];
  const float* b2  = (const float*)d_in[5];
  float* out = (float*)d_out;

  unsigned short* Wtf = (unsigned short*)d_ws;                   // 256 KiB
  unsigned short* P   = (unsigned short*)((char*)d_ws + 262144); // 48.83 MiB

  hipLaunchKernelGGL(pack_w_kernel, dim3(HID), dim3(128), 0, stream, W1, Wtf);
  hipLaunchKernelGGL(gemm_kernel, dim3(256), dim3(512), 0, stream, E, Wtf, b1, P);
  hipLaunchKernelGGL(edge_kernel, dim3(2048), dim3(256), 0, stream, idx, P, W2, b2, out);
}